// Round 3
// baseline (2144.997 us; speedup 1.0000x reference)
//
#include <hip/hip_runtime.h>
#include <hip/hip_bf16.h>
#include <math.h>

#define HW 512
#define NPIX (HW*HW)

typedef __hip_bfloat16 bf16;

__device__ __forceinline__ float b2f(bf16 v) { return __bfloat162float(v); }
__device__ __forceinline__ bf16 f2b(float v) { return __float2bfloat16(v); }

// ---------------- zero small accumulator region ----------------
__global__ __launch_bounds__(256) void k_zero(float* __restrict__ p, int n)
{
    int i = blockIdx.x*256 + threadIdx.x;
    if (i < n) p[i] = 0.f;
}

// ---------------- patch embed: 3x3 conv, 3 -> 48 ----------------
__global__ __launch_bounds__(256) void k_pe(const float* __restrict__ x,
                                            const float* __restrict__ w,
                                            float* __restrict__ out)
{
    __shared__ float ws[48*27];
    for (int i = threadIdx.x; i < 48*27; i += 256) ws[i] = w[i];
    __syncthreads();
    int p = blockIdx.x*256 + threadIdx.x;
    int py = p >> 9, px = p & 511;
    float in[27];
#pragma unroll
    for (int c = 0; c < 3; c++)
#pragma unroll
        for (int ky = 0; ky < 3; ky++)
#pragma unroll
            for (int kx = 0; kx < 3; kx++) {
                int yy = py + ky - 1, xx = px + kx - 1;
                float v = 0.f;
                if (yy >= 0 && yy < HW && xx >= 0 && xx < HW)
                    v = x[(size_t)c*NPIX + yy*HW + xx];
                in[(c*3+ky)*3+kx] = v;
            }
    for (int oc = 0; oc < 48; oc++) {
        const float* wr = &ws[oc*27];
        float acc = 0.f;
#pragma unroll
        for (int i = 0; i < 27; i++) acc += in[i]*wr[i];
        out[(size_t)oc*NPIX + p] = acc;
    }
}

// ---------------- fused channel-LayerNorm + 1x1 conv (48 -> OC), bf16 out ----------------
template<int OC>
__global__ __launch_bounds__(256) void k_ln_mm(const float* __restrict__ in,
                                               const float* __restrict__ lnw,
                                               const float* __restrict__ lnb,
                                               const float* __restrict__ W,
                                               bf16* __restrict__ out)
{
    __shared__ float ws[OC*48];
    __shared__ float lw[48], lb[48];
    for (int i = threadIdx.x; i < OC*48; i += 256) ws[i] = W[i];
    if (threadIdx.x < 48) { lw[threadIdx.x] = lnw[threadIdx.x]; lb[threadIdx.x] = lnb[threadIdx.x]; }
    __syncthreads();
    int p = blockIdx.x*256 + threadIdx.x;
    float y[48];
    float mu = 0.f;
#pragma unroll
    for (int i = 0; i < 48; i++) { y[i] = in[(size_t)i*NPIX + p]; mu += y[i]; }
    mu *= (1.f/48.f);
    float var = 0.f;
#pragma unroll
    for (int i = 0; i < 48; i++) { float d = y[i]-mu; var += d*d; }
    var *= (1.f/48.f);
    float s = rsqrtf(var + 1e-5f);
#pragma unroll
    for (int i = 0; i < 48; i++) y[i] = (y[i]-mu)*s*lw[i] + lb[i];
    for (int oc = 0; oc < OC; oc++) {
        const float4* wr = (const float4*)&ws[oc*48];
        float acc = 0.f;
#pragma unroll
        for (int i = 0; i < 12; i++) {
            float4 w4 = wr[i];
            acc += w4.x*y[4*i] + w4.y*y[4*i+1] + w4.z*y[4*i+2] + w4.w*y[4*i+3];
        }
        out[(size_t)oc*NPIX + p] = f2b(acc);
    }
}

// ---------------- depthwise 3x3 (bf16 -> bf16, fp32 weights) ----------------
__global__ __launch_bounds__(256) void k_dw(const bf16* __restrict__ in,
                                            const float* __restrict__ w,
                                            bf16* __restrict__ out)
{
    int ch = blockIdx.y;
    int p = blockIdx.x*256 + threadIdx.x;
    int py = p >> 9, px = p & 511;
    const bf16* ip = in + (size_t)ch*NPIX;
    float wk[9];
#pragma unroll
    for (int i = 0; i < 9; i++) wk[i] = w[ch*9+i];
    float acc = 0.f;
#pragma unroll
    for (int ky = 0; ky < 3; ky++) {
        int yy = py+ky-1;
        if (yy < 0 || yy >= HW) continue;
#pragma unroll
        for (int kx = 0; kx < 3; kx++) {
            int xx = px+kx-1;
            if (xx < 0 || xx >= HW) continue;
            acc += b2f(ip[yy*HW+xx])*wk[ky*3+kx];
        }
    }
    out[(size_t)ch*NPIX + p] = f2b(acc);
}

// ---------------- per-channel sum of squares (96 channels: q then k) ----------------
__global__ __launch_bounds__(256) void k_sumsq(const bf16* __restrict__ q,
                                               float* __restrict__ out)
{
    int ch = blockIdx.y;
    const bf16* p = q + (size_t)ch*NPIX + (size_t)blockIdx.x*(NPIX/16);
    float s = 0.f;
    for (int k = threadIdx.x; k < NPIX/16; k += 256) { float v = b2f(p[k]); s += v*v; }
#pragma unroll
    for (int off = 32; off; off >>= 1) s += __shfl_down(s, off);
    __shared__ float red[4];
    if ((threadIdx.x & 63) == 0) red[threadIdx.x >> 6] = s;
    __syncthreads();
    if (threadIdx.x == 0) atomicAdd(&out[ch], red[0]+red[1]+red[2]+red[3]);
}

// ---------------- S = Q K^T (48x48, K-dim = NPIX) ----------------
#define QKT_PIX 2048
__global__ __launch_bounds__(256) void k_qkt(const bf16* __restrict__ q,
                                             const bf16* __restrict__ k,
                                             float* __restrict__ S)
{
    __shared__ float qs[48][65];
    __shared__ float ks[48][65];
    int tx = threadIdx.x & 15, ty = threadIdx.x >> 4;
    float acc[3][3];
#pragma unroll
    for (int i = 0; i < 3; i++)
#pragma unroll
        for (int j = 0; j < 3; j++) acc[i][j] = 0.f;

    int base0 = blockIdx.x * QKT_PIX;
    for (int base = base0; base < base0 + QKT_PIX; base += 64) {
#pragma unroll
        for (int it = 0; it < 12; it++) {
            int c  = (threadIdx.x >> 6) + (it << 2);
            int pp = threadIdx.x & 63;
            qs[c][pp] = b2f(q[(size_t)c*NPIX + base + pp]);
            ks[c][pp] = b2f(k[(size_t)c*NPIX + base + pp]);
        }
        __syncthreads();
#pragma unroll 4
        for (int pp = 0; pp < 64; pp++) {
            float qv[3], kv[3];
#pragma unroll
            for (int i = 0; i < 3; i++) { qv[i] = qs[ty+16*i][pp]; kv[i] = ks[tx+16*i][pp]; }
#pragma unroll
            for (int i = 0; i < 3; i++)
#pragma unroll
                for (int j = 0; j < 3; j++) acc[i][j] += qv[i]*kv[j];
        }
        __syncthreads();
    }
#pragma unroll
    for (int i = 0; i < 3; i++)
#pragma unroll
        for (int j = 0; j < 3; j++)
            atomicAdd(&S[(ty+16*i)*48 + (tx+16*j)], acc[i][j]);
}

// ---------------- finalize: normalize, softmax, M = po_w @ attn ----------------
__global__ __launch_bounds__(256) void k_attn_final(const float* __restrict__ S,
                                                    const float* __restrict__ sumsq,
                                                    const float* __restrict__ po_w,
                                                    const float* __restrict__ temp,
                                                    float* __restrict__ M)
{
    __shared__ float attn[48][48];
    __shared__ float nrm[96];
    int t = threadIdx.x;
    if (t < 96) nrm[t] = fmaxf(sqrtf(sumsq[t]), 1e-12f);
    __syncthreads();
    float tmp = temp[0];
    if (t < 48) {
        float row[48];
        float mx = -1e30f;
#pragma unroll
        for (int d = 0; d < 48; d++) {
            float l = S[t*48+d] / (nrm[t]*nrm[48+d]) * tmp;
            row[d] = l; mx = fmaxf(mx, l);
        }
        float sum = 0.f;
#pragma unroll
        for (int d = 0; d < 48; d++) { float e = expf(row[d]-mx); sum += e; row[d] = e; }
        float inv = 1.f/sum;
#pragma unroll
        for (int d = 0; d < 48; d++) attn[t][d] = row[d]*inv;
    }
    __syncthreads();
    for (int idx = t; idx < 2304; idx += 256) {
        int cp = idx/48, d = idx%48;
        float acc = 0.f;
#pragma unroll
        for (int c = 0; c < 48; c++) acc += po_w[cp*48+c] * attn[c][d];
        M[idx] = acc;
    }
}

// ---------------- first = patch + M @ v (in place over fp32 patch) ----------------
__global__ __launch_bounds__(256) void k_attnv(const bf16* __restrict__ v,
                                               const float* __restrict__ M,
                                               float* __restrict__ patch)
{
    __shared__ float Ms[48*48];
    for (int i = threadIdx.x; i < 2304; i += 256) Ms[i] = M[i];
    __syncthreads();
    int p = blockIdx.x*256 + threadIdx.x;
    float vv[48];
#pragma unroll
    for (int i = 0; i < 48; i++) vv[i] = b2f(v[(size_t)i*NPIX + p]);
    for (int oc = 0; oc < 48; oc++) {
        const float4* wr = (const float4*)&Ms[oc*48];
        float acc = 0.f;
#pragma unroll
        for (int i = 0; i < 12; i++) {
            float4 w4 = wr[i];
            acc += w4.x*vv[4*i] + w4.y*vv[4*i+1] + w4.z*vv[4*i+2] + w4.w*vv[4*i+3];
        }
        patch[(size_t)oc*NPIX + p] += acc;
    }
}

// ---------------- depthwise 3x3 on both halves + gelu(x1)*x2 ----------------
__global__ __launch_bounds__(256) void k_dw_glu(const bf16* __restrict__ h1,
                                                const float* __restrict__ w,
                                                bf16* __restrict__ g)
{
    int ch = blockIdx.y;   // 0..126
    int p = blockIdx.x*256 + threadIdx.x;
    int py = p >> 9, px = p & 511;
    float w1[9], w2[9];
#pragma unroll
    for (int i = 0; i < 9; i++) { w1[i] = w[ch*9+i]; w2[i] = w[(ch+127)*9+i]; }
    const bf16* i1 = h1 + (size_t)ch*NPIX;
    const bf16* i2 = h1 + (size_t)(ch+127)*NPIX;
    float a1 = 0.f, a2 = 0.f;
#pragma unroll
    for (int ky = 0; ky < 3; ky++) {
        int yy = py+ky-1;
        if (yy < 0 || yy >= HW) continue;
#pragma unroll
        for (int kx = 0; kx < 3; kx++) {
            int xx = px+kx-1;
            if (xx < 0 || xx >= HW) continue;
            int o = yy*HW+xx;
            a1 += b2f(i1[o])*w1[ky*3+kx];
            a2 += b2f(i2[o])*w2[ky*3+kx];
        }
    }
    float ge = 0.5f*a1*(1.f + erff(a1*0.70710678118654752f));
    g[(size_t)ch*NPIX + p] = f2b(ge*a2);
}

// ---------------- fo 1x1 conv (127 -> 48) + residual, fp32 store ----------------
__global__ __launch_bounds__(256) void k_fo(const bf16* __restrict__ g,
                                            const float* __restrict__ W,
                                            const float* __restrict__ first,
                                            float* __restrict__ out)
{
    __shared__ float ws[48*128];
    for (int i = threadIdx.x; i < 48*128; i += 256) {
        int oc = i >> 7, ic = i & 127;
        ws[i] = (ic < 127) ? W[oc*127+ic] : 0.f;
    }
    __syncthreads();
    int p = blockIdx.x*256 + threadIdx.x;
    float acc[48];
#pragma unroll
    for (int i = 0; i < 48; i++) acc[i] = 0.f;
    for (int cb = 0; cb < 8; cb++) {
        float gv[16];
#pragma unroll
        for (int j = 0; j < 16; j++) {
            int ic = cb*16 + j;
            gv[j] = (ic < 127) ? b2f(g[(size_t)ic*NPIX + p]) : 0.f;
        }
        for (int oc = 0; oc < 48; oc++) {
            const float4* wr = (const float4*)&ws[oc*128 + cb*16];
            float a = acc[oc];
#pragma unroll
            for (int j = 0; j < 4; j++) {
                float4 w4 = wr[j];
                a += w4.x*gv[4*j] + w4.y*gv[4*j+1] + w4.z*gv[4*j+2] + w4.w*gv[4*j+3];
            }
            acc[oc] = a;
        }
    }
    for (int oc = 0; oc < 48; oc++)
        out[(size_t)oc*NPIX + p] = first[(size_t)oc*NPIX + p] + acc[oc];
}

extern "C" void kernel_launch(void* const* d_in, const int* in_sizes, int n_in,
                              void* d_out, int out_size, void* d_ws, size_t ws_size,
                              hipStream_t stream)
{
    const float* x     = (const float*)d_in[0];
    const float* pe_w  = (const float*)d_in[1];
    const float* n1w   = (const float*)d_in[2];
    const float* n1b   = (const float*)d_in[3];
    const float* temp  = (const float*)d_in[4];
    const float* qkvw  = (const float*)d_in[5];
    const float* qkvdw = (const float*)d_in[6];
    const float* pow_  = (const float*)d_in[7];
    const float* n2w   = (const float*)d_in[8];
    const float* n2b   = (const float*)d_in[9];
    const float* piw   = (const float*)d_in[10];
    const float* ffndw = (const float*)d_in[11];
    const float* fow   = (const float*)d_in[12];
    float* out = (float*)d_out;

    // ws layout, per-batch reuse (~240 MiB total):
    //   P  : 48 fp32 planes  [0, 48 MiB)          patch -> first
    //   A  : 144 bf16 planes [48, 120 MiB)        qkv pre-dw
    //   Bq : 144 bf16 planes [120, 192 MiB)       qkv post-dw (q,k,v)
    //   H1 : 254 bf16 planes [48, 175 MiB)        GDFN pre-dw (reuses A+Bq after attnv)
    //   G  : 127 bf16 planes [175, 238.5 MiB)     gelu(x1)*x2
    //   SM : fp32 @ 240 MiB: sumsq(96) + S(2304) + M(2304)
    float* P  = (float*)d_ws;
    bf16*  A  = (bf16*)(P + (size_t)48*NPIX);
    bf16*  Bq = A + (size_t)144*NPIX;
    bf16*  H1 = A;
    bf16*  G  = A + (size_t)254*NPIX;
    float* SM = (float*)(A + (size_t)384*NPIX);
    float* sumsq = SM;
    float* S  = SM + 96;
    float* M  = SM + 96 + 2304;

    dim3 blk(256);
    int nb = NPIX/256;

    for (int b = 0; b < 2; b++) {
        const float* xb   = x   + (size_t)b*3*NPIX;
        float*       outb = out + (size_t)b*48*NPIX;

        k_pe<<<dim3(nb), blk, 0, stream>>>(xb, pe_w, P);
        k_ln_mm<144><<<dim3(nb), blk, 0, stream>>>(P, n1w, n1b, qkvw, A);
        k_dw<<<dim3(nb, 144), blk, 0, stream>>>(A, qkvdw, Bq);
        k_zero<<<dim3(10), blk, 0, stream>>>(SM, 96 + 2304);
        k_sumsq<<<dim3(16, 96), blk, 0, stream>>>(Bq, sumsq);
        k_qkt<<<dim3(NPIX/QKT_PIX), blk, 0, stream>>>(Bq, Bq + (size_t)48*NPIX, S);
        k_attn_final<<<dim3(1), blk, 0, stream>>>(S, sumsq, pow_, temp, M);
        k_attnv<<<dim3(nb), blk, 0, stream>>>(Bq + (size_t)96*NPIX, M, P);
        k_ln_mm<254><<<dim3(nb), blk, 0, stream>>>(P, n2w, n2b, piw, H1);
        k_dw_glu<<<dim3(nb, 127), blk, 0, stream>>>(H1, ffndw, G);
        k_fo<<<dim3(nb), blk, 0, stream>>>(G, fow, P, outb);
    }
}

// Round 4
// 1433.645 us; speedup vs baseline: 1.4962x; 1.4962x over previous
//
#include <hip/hip_runtime.h>
#include <hip/hip_bf16.h>
#include <math.h>

#define HW 512
#define NPIX (HW*HW)

typedef __hip_bfloat16 bf16;
typedef __attribute__((ext_vector_type(8))) unsigned short u16x8;

__device__ __forceinline__ float b2f(bf16 v) { return __bfloat162float(v); }
__device__ __forceinline__ bf16 f2b(float v) { return __float2bfloat16(v); }

union fu { float f; unsigned int u; };
union bu { bf16 b; unsigned short u; };

__device__ __forceinline__ void ld_bf8(const bf16* p, float* f) {
    u16x8 u = *(const u16x8*)p;
#pragma unroll
    for (int j = 0; j < 8; j++) { fu c; c.u = ((unsigned int)u[j]) << 16; f[j] = c.f; }
}

__device__ __forceinline__ void st_bf8(bf16* p, const float* f) {
    u16x8 u;
#pragma unroll
    for (int j = 0; j < 8; j++) { bu c; c.b = f2b(f[j]); u[j] = c.u; }
    *(u16x8*)p = u;
}

// ---------------- zero small accumulator region ----------------
__global__ __launch_bounds__(256) void k_zero(float* __restrict__ p, int n)
{
    int i = blockIdx.x*256 + threadIdx.x;
    if (i < n) p[i] = 0.f;
}

// ---------------- patch embed: 3x3 conv, 3 -> 48 (wave-per-row, 8px/lane) ----------------
__global__ __launch_bounds__(256) void k_pe(const float* __restrict__ x,
                                            const float* __restrict__ w,
                                            float* __restrict__ out)
{
    __shared__ float ws[48*27];
    for (int i = threadIdx.x; i < 48*27; i += 256) ws[i] = w[i];
    __syncthreads();
    int lane = threadIdx.x & 63, wv = threadIdx.x >> 6;
    int row = blockIdx.x*4 + wv;
    int col = lane*8;
    float a[3][3][8];
    float lf[3][3], rt[3][3];
#pragma unroll
    for (int c = 0; c < 3; c++)
#pragma unroll
        for (int r = 0; r < 3; r++) {
            int rr = row + r - 1;
            if (rr >= 0 && rr < HW) {
                const float* p = x + (size_t)c*NPIX + rr*HW + col;
                float4 u0 = *(const float4*)p, u1 = *(const float4*)(p+4);
                a[c][r][0]=u0.x; a[c][r][1]=u0.y; a[c][r][2]=u0.z; a[c][r][3]=u0.w;
                a[c][r][4]=u1.x; a[c][r][5]=u1.y; a[c][r][6]=u1.z; a[c][r][7]=u1.w;
            } else {
#pragma unroll
                for (int j = 0; j < 8; j++) a[c][r][j] = 0.f;
            }
            float l = __shfl_up(a[c][r][7], 1);  lf[c][r] = (lane==0)  ? 0.f : l;
            float rv= __shfl_down(a[c][r][0],1); rt[c][r] = (lane==63) ? 0.f : rv;
        }
    for (int oc = 0; oc < 48; oc++) {
        float acc[8];
#pragma unroll
        for (int j = 0; j < 8; j++) acc[j] = 0.f;
#pragma unroll
        for (int c = 0; c < 3; c++)
#pragma unroll
            for (int r = 0; r < 3; r++) {
                float w0 = ws[oc*27 + c*9 + r*3 + 0];
                float w1 = ws[oc*27 + c*9 + r*3 + 1];
                float w2 = ws[oc*27 + c*9 + r*3 + 2];
#pragma unroll
                for (int j = 0; j < 8; j++) {
                    float xm = (j==0) ? lf[c][r] : a[c][r][j-1];
                    float x0 = a[c][r][j];
                    float xp = (j==7) ? rt[c][r] : a[c][r][j+1];
                    acc[j] += w0*xm + w1*x0 + w2*xp;
                }
            }
        float* po = out + (size_t)oc*NPIX + row*HW + col;
        *(float4*)po     = make_float4(acc[0],acc[1],acc[2],acc[3]);
        *(float4*)(po+4) = make_float4(acc[4],acc[5],acc[6],acc[7]);
    }
}

// ---------------- fused channel-LayerNorm + 1x1 conv (48 -> OC), 2px/thread ----------------
template<int OC>
__global__ __launch_bounds__(256) void k_ln_mm(const float* __restrict__ in,
                                               const float* __restrict__ lnw,
                                               const float* __restrict__ lnb,
                                               const float* __restrict__ W,
                                               bf16* __restrict__ out)
{
    __shared__ float ws[OC*48];
    __shared__ float lw[48], lb[48];
    for (int i = threadIdx.x; i < OC*48; i += 256) ws[i] = W[i];
    if (threadIdx.x < 48) { lw[threadIdx.x] = lnw[threadIdx.x]; lb[threadIdx.x] = lnb[threadIdx.x]; }
    __syncthreads();
    int p = (blockIdx.x*256 + threadIdx.x)*2;
    float y0[48], y1[48];
    float mu0 = 0.f, mu1 = 0.f;
#pragma unroll
    for (int i = 0; i < 48; i++) {
        float2 v = *(const float2*)&in[(size_t)i*NPIX + p];
        y0[i] = v.x; y1[i] = v.y; mu0 += v.x; mu1 += v.y;
    }
    mu0 *= (1.f/48.f); mu1 *= (1.f/48.f);
    float v0 = 0.f, v1 = 0.f;
#pragma unroll
    for (int i = 0; i < 48; i++) {
        float d0 = y0[i]-mu0, d1 = y1[i]-mu1;
        v0 += d0*d0; v1 += d1*d1;
    }
    float s0 = rsqrtf(v0*(1.f/48.f) + 1e-5f);
    float s1 = rsqrtf(v1*(1.f/48.f) + 1e-5f);
#pragma unroll
    for (int i = 0; i < 48; i++) {
        y0[i] = (y0[i]-mu0)*s0*lw[i] + lb[i];
        y1[i] = (y1[i]-mu1)*s1*lw[i] + lb[i];
    }
    for (int oc = 0; oc < OC; oc++) {
        const float4* wr = (const float4*)&ws[oc*48];
        float a0 = 0.f, a1 = 0.f;
#pragma unroll
        for (int i = 0; i < 12; i++) {
            float4 w4 = wr[i];
            a0 += w4.x*y0[4*i] + w4.y*y0[4*i+1] + w4.z*y0[4*i+2] + w4.w*y0[4*i+3];
            a1 += w4.x*y1[4*i] + w4.y*y1[4*i+1] + w4.z*y1[4*i+2] + w4.w*y1[4*i+3];
        }
        bu c0, c1; c0.b = f2b(a0); c1.b = f2b(a1);
        unsigned int word = (unsigned int)c0.u | ((unsigned int)c1.u << 16);
        *(unsigned int*)&out[(size_t)oc*NPIX + p] = word;
    }
}

// ---------------- depthwise 3x3 (bf16 -> bf16), wave-per-row 8px/lane ----------------
__global__ __launch_bounds__(256) void k_dw(const bf16* __restrict__ in,
                                            const float* __restrict__ w,
                                            bf16* __restrict__ out)
{
    int ch = blockIdx.y;
    int lane = threadIdx.x & 63, wv = threadIdx.x >> 6;
    int row = blockIdx.x*4 + wv;
    int col = lane*8;
    const bf16* ip = in + (size_t)ch*NPIX;
    float wk[9];
#pragma unroll
    for (int i = 0; i < 9; i++) wk[i] = w[ch*9+i];
    float a[3][8];
    float lf[3], rt[3];
#pragma unroll
    for (int r = 0; r < 3; r++) {
        int rr = row + r - 1;
        if (rr >= 0 && rr < HW) ld_bf8(ip + rr*HW + col, a[r]);
        else { for (int j = 0; j < 8; j++) a[r][j] = 0.f; }
        float l = __shfl_up(a[r][7], 1);  lf[r] = (lane==0)  ? 0.f : l;
        float rv= __shfl_down(a[r][0],1); rt[r] = (lane==63) ? 0.f : rv;
    }
    float o[8];
#pragma unroll
    for (int j = 0; j < 8; j++) {
        float s = 0.f;
#pragma unroll
        for (int r = 0; r < 3; r++) {
            float xm = (j==0) ? lf[r] : a[r][j-1];
            float x0 = a[r][j];
            float xp = (j==7) ? rt[r] : a[r][j+1];
            s += wk[r*3+0]*xm + wk[r*3+1]*x0 + wk[r*3+2]*xp;
        }
        o[j] = s;
    }
    st_bf8(out + (size_t)ch*NPIX + row*HW + col, o);
}

// ---------------- per-channel sum of squares (96 channels: q then k) ----------------
__global__ __launch_bounds__(256) void k_sumsq(const bf16* __restrict__ q,
                                               float* __restrict__ out)
{
    int ch = blockIdx.y;
    const bf16* p = q + (size_t)ch*NPIX + (size_t)blockIdx.x*(NPIX/16);
    float s = 0.f;
    for (int k = threadIdx.x*8; k < NPIX/16; k += 256*8) {
        float f[8]; ld_bf8(p + k, f);
#pragma unroll
        for (int j = 0; j < 8; j++) s += f[j]*f[j];
    }
#pragma unroll
    for (int off = 32; off; off >>= 1) s += __shfl_down(s, off);
    __shared__ float red[4];
    if ((threadIdx.x & 63) == 0) red[threadIdx.x >> 6] = s;
    __syncthreads();
    if (threadIdx.x == 0) atomicAdd(&out[ch], red[0]+red[1]+red[2]+red[3]);
}

// ---------------- S = Q K^T (48x48, K-dim = NPIX) ----------------
#define QKT_PIX 2048
__global__ __launch_bounds__(256) void k_qkt(const bf16* __restrict__ q,
                                             const bf16* __restrict__ k,
                                             float* __restrict__ S)
{
    __shared__ float qs[48][65];
    __shared__ float ks[48][65];
    int tx = threadIdx.x & 15, ty = threadIdx.x >> 4;
    float acc[3][3];
#pragma unroll
    for (int i = 0; i < 3; i++)
#pragma unroll
        for (int j = 0; j < 3; j++) acc[i][j] = 0.f;

    int base0 = blockIdx.x * QKT_PIX;
    for (int base = base0; base < base0 + QKT_PIX; base += 64) {
#pragma unroll
        for (int it = 0; it < 12; it++) {
            int c  = (threadIdx.x >> 6) + (it << 2);
            int pp = threadIdx.x & 63;
            qs[c][pp] = b2f(q[(size_t)c*NPIX + base + pp]);
            ks[c][pp] = b2f(k[(size_t)c*NPIX + base + pp]);
        }
        __syncthreads();
#pragma unroll 4
        for (int pp = 0; pp < 64; pp++) {
            float qv[3], kv[3];
#pragma unroll
            for (int i = 0; i < 3; i++) { qv[i] = qs[ty+16*i][pp]; kv[i] = ks[tx+16*i][pp]; }
#pragma unroll
            for (int i = 0; i < 3; i++)
#pragma unroll
                for (int j = 0; j < 3; j++) acc[i][j] += qv[i]*kv[j];
        }
        __syncthreads();
    }
#pragma unroll
    for (int i = 0; i < 3; i++)
#pragma unroll
        for (int j = 0; j < 3; j++)
            atomicAdd(&S[(ty+16*i)*48 + (tx+16*j)], acc[i][j]);
}

// ---------------- finalize: normalize, softmax, M = po_w @ attn ----------------
__global__ __launch_bounds__(256) void k_attn_final(const float* __restrict__ S,
                                                    const float* __restrict__ sumsq,
                                                    const float* __restrict__ po_w,
                                                    const float* __restrict__ temp,
                                                    float* __restrict__ M)
{
    __shared__ float attn[48][48];
    __shared__ float nrm[96];
    int t = threadIdx.x;
    if (t < 96) nrm[t] = fmaxf(sqrtf(sumsq[t]), 1e-12f);
    __syncthreads();
    float tmp = temp[0];
    if (t < 48) {
        float row[48];
        float mx = -1e30f;
#pragma unroll
        for (int d = 0; d < 48; d++) {
            float l = S[t*48+d] / (nrm[t]*nrm[48+d]) * tmp;
            row[d] = l; mx = fmaxf(mx, l);
        }
        float sum = 0.f;
#pragma unroll
        for (int d = 0; d < 48; d++) { float e = expf(row[d]-mx); sum += e; row[d] = e; }
        float inv = 1.f/sum;
#pragma unroll
        for (int d = 0; d < 48; d++) attn[t][d] = row[d]*inv;
    }
    __syncthreads();
    for (int idx = t; idx < 2304; idx += 256) {
        int cp = idx/48, d = idx%48;
        float acc = 0.f;
#pragma unroll
        for (int c = 0; c < 48; c++) acc += po_w[cp*48+c] * attn[c][d];
        M[idx] = acc;
    }
}

// ---------------- first = patch + M @ v (in place, 2px/thread) ----------------
__global__ __launch_bounds__(256) void k_attnv(const bf16* __restrict__ v,
                                               const float* __restrict__ M,
                                               float* __restrict__ patch)
{
    __shared__ float Ms[48*48];
    for (int i = threadIdx.x; i < 2304; i += 256) Ms[i] = M[i];
    __syncthreads();
    int p = (blockIdx.x*256 + threadIdx.x)*2;
    float v0[48], v1[48];
#pragma unroll
    for (int i = 0; i < 48; i++) {
        unsigned int word = *(const unsigned int*)&v[(size_t)i*NPIX + p];
        fu c0, c1; c0.u = word << 16; c1.u = word & 0xffff0000u;
        v0[i] = c0.f; v1[i] = c1.f;
    }
    for (int oc = 0; oc < 48; oc++) {
        const float4* wr = (const float4*)&Ms[oc*48];
        float a0 = 0.f, a1 = 0.f;
#pragma unroll
        for (int i = 0; i < 12; i++) {
            float4 w4 = wr[i];
            a0 += w4.x*v0[4*i] + w4.y*v0[4*i+1] + w4.z*v0[4*i+2] + w4.w*v0[4*i+3];
            a1 += w4.x*v1[4*i] + w4.y*v1[4*i+1] + w4.z*v1[4*i+2] + w4.w*v1[4*i+3];
        }
        float2* pp = (float2*)&patch[(size_t)oc*NPIX + p];
        float2 old = *pp;
        old.x += a0; old.y += a1;
        *pp = old;
    }
}

// ---------------- depthwise 3x3 both halves + gelu(x1)*x2, wave-per-row ----------------
__global__ __launch_bounds__(256) void k_dw_glu(const bf16* __restrict__ h1,
                                                const float* __restrict__ w,
                                                bf16* __restrict__ g)
{
    int ch = blockIdx.y;   // 0..126
    int lane = threadIdx.x & 63, wv = threadIdx.x >> 6;
    int row = blockIdx.x*4 + wv;
    int col = lane*8;
    float w1[9], w2[9];
#pragma unroll
    for (int i = 0; i < 9; i++) { w1[i] = w[ch*9+i]; w2[i] = w[(ch+127)*9+i]; }
    const bf16* i1 = h1 + (size_t)ch*NPIX;
    const bf16* i2 = h1 + (size_t)(ch+127)*NPIX;
    float a[3][8], b[3][8];
    float lfa[3], rta[3], lfb[3], rtb[3];
#pragma unroll
    for (int r = 0; r < 3; r++) {
        int rr = row + r - 1;
        if (rr >= 0 && rr < HW) {
            ld_bf8(i1 + rr*HW + col, a[r]);
            ld_bf8(i2 + rr*HW + col, b[r]);
        } else {
#pragma unroll
            for (int j = 0; j < 8; j++) { a[r][j] = 0.f; b[r][j] = 0.f; }
        }
        float l1 = __shfl_up(a[r][7],1);   lfa[r] = (lane==0)  ? 0.f : l1;
        float r1 = __shfl_down(a[r][0],1); rta[r] = (lane==63) ? 0.f : r1;
        float l2 = __shfl_up(b[r][7],1);   lfb[r] = (lane==0)  ? 0.f : l2;
        float r2 = __shfl_down(b[r][0],1); rtb[r] = (lane==63) ? 0.f : r2;
    }
    float o[8];
#pragma unroll
    for (int j = 0; j < 8; j++) {
        float s1 = 0.f, s2 = 0.f;
#pragma unroll
        for (int r = 0; r < 3; r++) {
            float xm = (j==0) ? lfa[r] : a[r][j-1];
            float x0 = a[r][j];
            float xp = (j==7) ? rta[r] : a[r][j+1];
            s1 += w1[r*3+0]*xm + w1[r*3+1]*x0 + w1[r*3+2]*xp;
            float ym = (j==0) ? lfb[r] : b[r][j-1];
            float y0 = b[r][j];
            float yp = (j==7) ? rtb[r] : b[r][j+1];
            s2 += w2[r*3+0]*ym + w2[r*3+1]*y0 + w2[r*3+2]*yp;
        }
        float ge = 0.5f*s1*(1.f + erff(s1*0.70710678118654752f));
        o[j] = ge*s2;
    }
    st_bf8(g + (size_t)ch*NPIX + row*HW + col, o);
}

// ---------------- fo 1x1 conv (127 -> 48) + residual, 2px/thread ----------------
__global__ __launch_bounds__(256) void k_fo(const bf16* __restrict__ g,
                                            const float* __restrict__ W,
                                            const float* __restrict__ first,
                                            float* __restrict__ out)
{
    __shared__ float ws[48*128];
    for (int i = threadIdx.x; i < 48*128; i += 256) {
        int oc = i >> 7, ic = i & 127;
        ws[i] = (ic < 127) ? W[oc*127+ic] : 0.f;
    }
    __syncthreads();
    int p = (blockIdx.x*256 + threadIdx.x)*2;
    float acc0[48], acc1[48];
#pragma unroll
    for (int i = 0; i < 48; i++) { acc0[i] = 0.f; acc1[i] = 0.f; }
    for (int cb = 0; cb < 8; cb++) {
        float g0[16], g1[16];
#pragma unroll
        for (int j = 0; j < 16; j++) {
            int ic = cb*16 + j;
            if (ic < 127) {
                unsigned int word = *(const unsigned int*)&g[(size_t)ic*NPIX + p];
                fu c0, c1; c0.u = word << 16; c1.u = word & 0xffff0000u;
                g0[j] = c0.f; g1[j] = c1.f;
            } else { g0[j] = 0.f; g1[j] = 0.f; }
        }
        for (int oc = 0; oc < 48; oc++) {
            const float4* wr = (const float4*)&ws[oc*128 + cb*16];
            float a0 = acc0[oc], a1 = acc1[oc];
#pragma unroll
            for (int j = 0; j < 4; j++) {
                float4 w4 = wr[j];
                a0 += w4.x*g0[4*j] + w4.y*g0[4*j+1] + w4.z*g0[4*j+2] + w4.w*g0[4*j+3];
                a1 += w4.x*g1[4*j] + w4.y*g1[4*j+1] + w4.z*g1[4*j+2] + w4.w*g1[4*j+3];
            }
            acc0[oc] = a0; acc1[oc] = a1;
        }
    }
    for (int oc = 0; oc < 48; oc++) {
        float2 f = *(const float2*)&first[(size_t)oc*NPIX + p];
        f.x += acc0[oc]; f.y += acc1[oc];
        *(float2*)&out[(size_t)oc*NPIX + p] = f;
    }
}

extern "C" void kernel_launch(void* const* d_in, const int* in_sizes, int n_in,
                              void* d_out, int out_size, void* d_ws, size_t ws_size,
                              hipStream_t stream)
{
    const float* x     = (const float*)d_in[0];
    const float* pe_w  = (const float*)d_in[1];
    const float* n1w   = (const float*)d_in[2];
    const float* n1b   = (const float*)d_in[3];
    const float* temp  = (const float*)d_in[4];
    const float* qkvw  = (const float*)d_in[5];
    const float* qkvdw = (const float*)d_in[6];
    const float* pow_  = (const float*)d_in[7];
    const float* n2w   = (const float*)d_in[8];
    const float* n2b   = (const float*)d_in[9];
    const float* piw   = (const float*)d_in[10];
    const float* ffndw = (const float*)d_in[11];
    const float* fow   = (const float*)d_in[12];
    float* out = (float*)d_out;

    float* P  = (float*)d_ws;
    bf16*  A  = (bf16*)(P + (size_t)48*NPIX);
    bf16*  Bq = A + (size_t)144*NPIX;
    bf16*  H1 = A;
    bf16*  G  = A + (size_t)254*NPIX;
    float* SM = (float*)(A + (size_t)384*NPIX);
    float* sumsq = SM;
    float* S  = SM + 96;
    float* M  = SM + 96 + 2304;

    dim3 blk(256);
    int nb  = NPIX/256;
    int nb2 = NPIX/512;   // 2px/thread kernels
    int nr  = HW/4;       // wave-per-row kernels: 4 rows/block

    for (int b = 0; b < 2; b++) {
        const float* xb   = x   + (size_t)b*3*NPIX;
        float*       outb = out + (size_t)b*48*NPIX;

        k_pe<<<dim3(nr), blk, 0, stream>>>(xb, pe_w, P);
        k_ln_mm<144><<<dim3(nb2), blk, 0, stream>>>(P, n1w, n1b, qkvw, A);
        k_dw<<<dim3(nr, 144), blk, 0, stream>>>(A, qkvdw, Bq);
        k_zero<<<dim3(10), blk, 0, stream>>>(SM, 96 + 2304);
        k_sumsq<<<dim3(16, 96), blk, 0, stream>>>(Bq, sumsq);
        k_qkt<<<dim3(NPIX/QKT_PIX), blk, 0, stream>>>(Bq, Bq + (size_t)48*NPIX, S);
        k_attn_final<<<dim3(1), blk, 0, stream>>>(S, sumsq, pow_, temp, M);
        k_attnv<<<dim3(nb2), blk, 0, stream>>>(Bq + (size_t)96*NPIX, M, P);
        k_ln_mm<254><<<dim3(nb2), blk, 0, stream>>>(P, n2w, n2b, piw, H1);
        k_dw_glu<<<dim3(nr, 127), blk, 0, stream>>>(H1, ffndw, G);
        k_fo<<<dim3(nb2), blk, 0, stream>>>(G, fow, P, outb);
    }
}

// Round 5
// 1176.584 us; speedup vs baseline: 1.8231x; 1.2185x over previous
//
#include <hip/hip_runtime.h>
#include <hip/hip_bf16.h>
#include <math.h>

#define HW 512
#define NPIX (HW*HW)

typedef __hip_bfloat16 bf16;
typedef __attribute__((ext_vector_type(8))) unsigned short u16x8;
typedef __attribute__((ext_vector_type(8))) short s16x8;
typedef __attribute__((ext_vector_type(4))) float f32x4;

__device__ __forceinline__ float b2f(bf16 v) { return __bfloat162float(v); }
__device__ __forceinline__ bf16 f2b(float v) { return __float2bfloat16(v); }

union fu { float f; unsigned int u; };
union bu { bf16 b; unsigned short u; };

__device__ __forceinline__ void ld_bf8(const bf16* p, float* f) {
    u16x8 u = *(const u16x8*)p;
#pragma unroll
    for (int j = 0; j < 8; j++) { fu c; c.u = ((unsigned int)u[j]) << 16; f[j] = c.f; }
}

__device__ __forceinline__ void st_bf8(bf16* p, const float* f) {
    u16x8 u;
#pragma unroll
    for (int j = 0; j < 8; j++) { bu c; c.b = f2b(f[j]); u[j] = c.u; }
    *(u16x8*)p = u;
}

// ---------------- zero small accumulator region ----------------
__global__ __launch_bounds__(256) void k_zero(float* __restrict__ p, int n)
{
    int i = blockIdx.x*256 + threadIdx.x;
    if (i < n) p[i] = 0.f;
}

// ---------------- weight prep: fp32 [OC_REAL][48] -> bf16 [OC_PAD][64], zero-padded ----------------
__global__ __launch_bounds__(256) void k_wprep(const float* __restrict__ W,
                                               bf16* __restrict__ wpad,
                                               int oc_real, int oc_pad)
{
    int idx = blockIdx.x*256 + threadIdx.x;
    if (idx >= oc_pad*64) return;
    int oc = idx >> 6, k = idx & 63;
    float v = (oc < oc_real && k < 48) ? W[oc*48 + k] : 0.f;
    wpad[idx] = f2b(v);
}

// ---------------- patch embed: 3x3 conv, 3 -> 48 (wave-per-row, 8px/lane) ----------------
__global__ __launch_bounds__(256) void k_pe(const float* __restrict__ x,
                                            const float* __restrict__ w,
                                            float* __restrict__ out)
{
    __shared__ float ws[48*27];
    for (int i = threadIdx.x; i < 48*27; i += 256) ws[i] = w[i];
    __syncthreads();
    int lane = threadIdx.x & 63, wv = threadIdx.x >> 6;
    int row = blockIdx.x*4 + wv;
    int col = lane*8;
    float a[3][3][8];
    float lf[3][3], rt[3][3];
#pragma unroll
    for (int c = 0; c < 3; c++)
#pragma unroll
        for (int r = 0; r < 3; r++) {
            int rr = row + r - 1;
            if (rr >= 0 && rr < HW) {
                const float* p = x + (size_t)c*NPIX + rr*HW + col;
                float4 u0 = *(const float4*)p, u1 = *(const float4*)(p+4);
                a[c][r][0]=u0.x; a[c][r][1]=u0.y; a[c][r][2]=u0.z; a[c][r][3]=u0.w;
                a[c][r][4]=u1.x; a[c][r][5]=u1.y; a[c][r][6]=u1.z; a[c][r][7]=u1.w;
            } else {
#pragma unroll
                for (int j = 0; j < 8; j++) a[c][r][j] = 0.f;
            }
            float l = __shfl_up(a[c][r][7], 1);  lf[c][r] = (lane==0)  ? 0.f : l;
            float rv= __shfl_down(a[c][r][0],1); rt[c][r] = (lane==63) ? 0.f : rv;
        }
    for (int oc = 0; oc < 48; oc++) {
        float acc[8];
#pragma unroll
        for (int j = 0; j < 8; j++) acc[j] = 0.f;
#pragma unroll
        for (int c = 0; c < 3; c++)
#pragma unroll
            for (int r = 0; r < 3; r++) {
                float w0 = ws[oc*27 + c*9 + r*3 + 0];
                float w1 = ws[oc*27 + c*9 + r*3 + 1];
                float w2 = ws[oc*27 + c*9 + r*3 + 2];
#pragma unroll
                for (int j = 0; j < 8; j++) {
                    float xm = (j==0) ? lf[c][r] : a[c][r][j-1];
                    float x0 = a[c][r][j];
                    float xp = (j==7) ? rt[c][r] : a[c][r][j+1];
                    acc[j] += w0*xm + w1*x0 + w2*xp;
                }
            }
        float* po = out + (size_t)oc*NPIX + row*HW + col;
        *(float4*)po     = make_float4(acc[0],acc[1],acc[2],acc[3]);
        *(float4*)(po+4) = make_float4(acc[4],acc[5],acc[6],acc[7]);
    }
}

// ---------------- fused channel-LayerNorm + 1x1 conv via MFMA (48 -> OC) ----------------
// MFMA 16x16x32 bf16. Layouts (guide-verified):
//   A[m][k]: m=lane&15, k=(lane>>4)*8+j      (short8)
//   B[k][n]: n=lane&15, k=(lane>>4)*8+j      (short8)
//   D[m][n]: n=lane&15, m=(lane>>4)*4+reg    (float4)
// K padded 48->64 (zeros), OC padded to mult of 16; swizzled LDS for y.
template<int OC_PAD, int OC_REAL, int MT_PER_WAVE>
__global__ __launch_bounds__(256) void k_ln_mm_mfma(const float* __restrict__ in,
                                                    const float* __restrict__ lnw,
                                                    const float* __restrict__ lnb,
                                                    const s16x8* __restrict__ wpad,  // [OC_PAD][8 blocks]
                                                    bf16* __restrict__ out)
{
    constexpr int NMT = OC_PAD/16;
    __shared__ s16x8 y_lds[256*8];
    __shared__ float lw[48], lb[48];
    int t = threadIdx.x;
    if (t < 48) { lw[t] = lnw[t]; lb[t] = lnb[t]; }
    int base = blockIdx.x*256;
    int px = base + t;
    float y[48];
    float mu = 0.f;
#pragma unroll
    for (int i = 0; i < 48; i++) { y[i] = in[(size_t)i*NPIX + px]; mu += y[i]; }
    mu *= (1.f/48.f);
    float var = 0.f;
#pragma unroll
    for (int i = 0; i < 48; i++) { float d = y[i]-mu; var += d*d; }
    float s = rsqrtf(var*(1.f/48.f) + 1e-5f);
    __syncthreads();   // lw/lb visible
#pragma unroll
    for (int i = 0; i < 48; i++) y[i] = (y[i]-mu)*s*lw[i] + lb[i];
    // pack to LDS, swizzled 16B blocks
#pragma unroll
    for (int kb = 0; kb < 8; kb++) {
        union { s16x8 v; unsigned short us[8]; } pk;
#pragma unroll
        for (int j = 0; j < 8; j++) {
            int c = kb*8 + j;
            bu b; b.b = f2b(c < 48 ? y[c] : 0.f);
            pk.us[j] = (c < 48) ? b.u : (unsigned short)0;
        }
        y_lds[t*8 + (kb ^ (t & 7))] = pk.v;
    }
    __syncthreads();

    int lane = t & 63, wv = t >> 6;
    int q = lane >> 4, n = lane & 15;
    // A fragments from global (L2-resident)
    s16x8 a[MT_PER_WAVE][2];
#pragma unroll
    for (int mi = 0; mi < MT_PER_WAVE; mi++) {
        int mt = wv + 4*mi;
        if (mt < NMT) {
            int oc = mt*16 + n;
            a[mi][0] = wpad[oc*8 + q];
            a[mi][1] = wpad[oc*8 + 4 + q];
        }
    }
#pragma unroll 1
    for (int nt = 0; nt < 16; nt++) {
        int npx = nt*16 + n;
        s16x8 b0 = y_lds[npx*8 + (q ^ (npx & 7))];
        s16x8 b1 = y_lds[npx*8 + ((4 + q) ^ (npx & 7))];
        size_t pxg = base + npx;
#pragma unroll
        for (int mi = 0; mi < MT_PER_WAVE; mi++) {
            int mt = wv + 4*mi;
            if (mt >= NMT) continue;
            f32x4 acc = {0.f, 0.f, 0.f, 0.f};
            acc = __builtin_amdgcn_mfma_f32_16x16x32_bf16(a[mi][0], b0, acc, 0, 0, 0);
            acc = __builtin_amdgcn_mfma_f32_16x16x32_bf16(a[mi][1], b1, acc, 0, 0, 0);
            int ocb = mt*16 + q*4;
#pragma unroll
            for (int r = 0; r < 4; r++) {
                int oc = ocb + r;
                if (OC_REAL == OC_PAD || oc < OC_REAL)
                    out[(size_t)oc*NPIX + pxg] = f2b(acc[r]);
            }
        }
    }
}

// ---------------- depthwise 3x3 (bf16 -> bf16), wave-per-row 8px/lane ----------------
__global__ __launch_bounds__(256) void k_dw(const bf16* __restrict__ in,
                                            const float* __restrict__ w,
                                            bf16* __restrict__ out)
{
    int ch = blockIdx.y;
    int lane = threadIdx.x & 63, wv = threadIdx.x >> 6;
    int row = blockIdx.x*4 + wv;
    int col = lane*8;
    const bf16* ip = in + (size_t)ch*NPIX;
    float wk[9];
#pragma unroll
    for (int i = 0; i < 9; i++) wk[i] = w[ch*9+i];
    float a[3][8];
    float lf[3], rt[3];
#pragma unroll
    for (int r = 0; r < 3; r++) {
        int rr = row + r - 1;
        if (rr >= 0 && rr < HW) ld_bf8(ip + rr*HW + col, a[r]);
        else { for (int j = 0; j < 8; j++) a[r][j] = 0.f; }
        float l = __shfl_up(a[r][7], 1);  lf[r] = (lane==0)  ? 0.f : l;
        float rv= __shfl_down(a[r][0],1); rt[r] = (lane==63) ? 0.f : rv;
    }
    float o[8];
#pragma unroll
    for (int j = 0; j < 8; j++) {
        float s = 0.f;
#pragma unroll
        for (int r = 0; r < 3; r++) {
            float xm = (j==0) ? lf[r] : a[r][j-1];
            float x0 = a[r][j];
            float xp = (j==7) ? rt[r] : a[r][j+1];
            s += wk[r*3+0]*xm + wk[r*3+1]*x0 + wk[r*3+2]*xp;
        }
        o[j] = s;
    }
    st_bf8(out + (size_t)ch*NPIX + row*HW + col, o);
}

// ---------------- per-channel sum of squares (96 channels: q then k) ----------------
__global__ __launch_bounds__(256) void k_sumsq(const bf16* __restrict__ q,
                                               float* __restrict__ out)
{
    int ch = blockIdx.y;
    const bf16* p = q + (size_t)ch*NPIX + (size_t)blockIdx.x*(NPIX/16);
    float s = 0.f;
    for (int k = threadIdx.x*8; k < NPIX/16; k += 256*8) {
        float f[8]; ld_bf8(p + k, f);
#pragma unroll
        for (int j = 0; j < 8; j++) s += f[j]*f[j];
    }
#pragma unroll
    for (int off = 32; off; off >>= 1) s += __shfl_down(s, off);
    __shared__ float red[4];
    if ((threadIdx.x & 63) == 0) red[threadIdx.x >> 6] = s;
    __syncthreads();
    if (threadIdx.x == 0) atomicAdd(&out[ch], red[0]+red[1]+red[2]+red[3]);
}

// ---------------- S = Q K^T (48x48, K-dim = NPIX) ----------------
#define QKT_PIX 2048
__global__ __launch_bounds__(256) void k_qkt(const bf16* __restrict__ q,
                                             const bf16* __restrict__ k,
                                             float* __restrict__ S)
{
    __shared__ float qs[48][65];
    __shared__ float ks[48][65];
    int tx = threadIdx.x & 15, ty = threadIdx.x >> 4;
    float acc[3][3];
#pragma unroll
    for (int i = 0; i < 3; i++)
#pragma unroll
        for (int j = 0; j < 3; j++) acc[i][j] = 0.f;

    int base0 = blockIdx.x * QKT_PIX;
    for (int base = base0; base < base0 + QKT_PIX; base += 64) {
#pragma unroll
        for (int it = 0; it < 12; it++) {
            int c  = (threadIdx.x >> 6) + (it << 2);
            int pp = threadIdx.x & 63;
            qs[c][pp] = b2f(q[(size_t)c*NPIX + base + pp]);
            ks[c][pp] = b2f(k[(size_t)c*NPIX + base + pp]);
        }
        __syncthreads();
#pragma unroll 4
        for (int pp = 0; pp < 64; pp++) {
            float qv[3], kv[3];
#pragma unroll
            for (int i = 0; i < 3; i++) { qv[i] = qs[ty+16*i][pp]; kv[i] = ks[tx+16*i][pp]; }
#pragma unroll
            for (int i = 0; i < 3; i++)
#pragma unroll
                for (int j = 0; j < 3; j++) acc[i][j] += qv[i]*kv[j];
        }
        __syncthreads();
    }
#pragma unroll
    for (int i = 0; i < 3; i++)
#pragma unroll
        for (int j = 0; j < 3; j++)
            atomicAdd(&S[(ty+16*i)*48 + (tx+16*j)], acc[i][j]);
}

// ---------------- finalize: normalize, softmax, M = po_w @ attn ----------------
__global__ __launch_bounds__(256) void k_attn_final(const float* __restrict__ S,
                                                    const float* __restrict__ sumsq,
                                                    const float* __restrict__ po_w,
                                                    const float* __restrict__ temp,
                                                    float* __restrict__ M)
{
    __shared__ float attn[48][48];
    __shared__ float nrm[96];
    int t = threadIdx.x;
    if (t < 96) nrm[t] = fmaxf(sqrtf(sumsq[t]), 1e-12f);
    __syncthreads();
    float tmp = temp[0];
    if (t < 48) {
        float row[48];
        float mx = -1e30f;
#pragma unroll
        for (int d = 0; d < 48; d++) {
            float l = S[t*48+d] / (nrm[t]*nrm[48+d]) * tmp;
            row[d] = l; mx = fmaxf(mx, l);
        }
        float sum = 0.f;
#pragma unroll
        for (int d = 0; d < 48; d++) { float e = expf(row[d]-mx); sum += e; row[d] = e; }
        float inv = 1.f/sum;
#pragma unroll
        for (int d = 0; d < 48; d++) attn[t][d] = row[d]*inv;
    }
    __syncthreads();
    for (int idx = t; idx < 2304; idx += 256) {
        int cp = idx/48, d = idx%48;
        float acc = 0.f;
#pragma unroll
        for (int c = 0; c < 48; c++) acc += po_w[cp*48+c] * attn[c][d];
        M[idx] = acc;
    }
}

// ---------------- first = patch + M @ v (in place, 2px/thread) ----------------
__global__ __launch_bounds__(256) void k_attnv(const bf16* __restrict__ v,
                                               const float* __restrict__ M,
                                               float* __restrict__ patch)
{
    __shared__ float Ms[48*48];
    for (int i = threadIdx.x; i < 2304; i += 256) Ms[i] = M[i];
    __syncthreads();
    int p = (blockIdx.x*256 + threadIdx.x)*2;
    float v0[48], v1[48];
#pragma unroll
    for (int i = 0; i < 48; i++) {
        unsigned int word = *(const unsigned int*)&v[(size_t)i*NPIX + p];
        fu c0, c1; c0.u = word << 16; c1.u = word & 0xffff0000u;
        v0[i] = c0.f; v1[i] = c1.f;
    }
    for (int oc = 0; oc < 48; oc++) {
        const float4* wr = (const float4*)&Ms[oc*48];
        float a0 = 0.f, a1 = 0.f;
#pragma unroll
        for (int i = 0; i < 12; i++) {
            float4 w4 = wr[i];
            a0 += w4.x*v0[4*i] + w4.y*v0[4*i+1] + w4.z*v0[4*i+2] + w4.w*v0[4*i+3];
            a1 += w4.x*v1[4*i] + w4.y*v1[4*i+1] + w4.z*v1[4*i+2] + w4.w*v1[4*i+3];
        }
        float2* pp = (float2*)&patch[(size_t)oc*NPIX + p];
        float2 old = *pp;
        old.x += a0; old.y += a1;
        *pp = old;
    }
}

// ---------------- depthwise 3x3 both halves + gelu(x1)*x2, wave-per-row ----------------
__global__ __launch_bounds__(256) void k_dw_glu(const bf16* __restrict__ h1,
                                                const float* __restrict__ w,
                                                bf16* __restrict__ g)
{
    int ch = blockIdx.y;   // 0..126
    int lane = threadIdx.x & 63, wv = threadIdx.x >> 6;
    int row = blockIdx.x*4 + wv;
    int col = lane*8;
    float w1[9], w2[9];
#pragma unroll
    for (int i = 0; i < 9; i++) { w1[i] = w[ch*9+i]; w2[i] = w[(ch+127)*9+i]; }
    const bf16* i1 = h1 + (size_t)ch*NPIX;
    const bf16* i2 = h1 + (size_t)(ch+127)*NPIX;
    float a[3][8], b[3][8];
    float lfa[3], rta[3], lfb[3], rtb[3];
#pragma unroll
    for (int r = 0; r < 3; r++) {
        int rr = row + r - 1;
        if (rr >= 0 && rr < HW) {
            ld_bf8(i1 + rr*HW + col, a[r]);
            ld_bf8(i2 + rr*HW + col, b[r]);
        } else {
#pragma unroll
            for (int j = 0; j < 8; j++) { a[r][j] = 0.f; b[r][j] = 0.f; }
        }
        float l1 = __shfl_up(a[r][7],1);   lfa[r] = (lane==0)  ? 0.f : l1;
        float r1 = __shfl_down(a[r][0],1); rta[r] = (lane==63) ? 0.f : r1;
        float l2 = __shfl_up(b[r][7],1);   lfb[r] = (lane==0)  ? 0.f : l2;
        float r2 = __shfl_down(b[r][0],1); rtb[r] = (lane==63) ? 0.f : r2;
    }
    float o[8];
#pragma unroll
    for (int j = 0; j < 8; j++) {
        float s1 = 0.f, s2 = 0.f;
#pragma unroll
        for (int r = 0; r < 3; r++) {
            float xm = (j==0) ? lfa[r] : a[r][j-1];
            float x0 = a[r][j];
            float xp = (j==7) ? rta[r] : a[r][j+1];
            s1 += w1[r*3+0]*xm + w1[r*3+1]*x0 + w1[r*3+2]*xp;
            float ym = (j==0) ? lfb[r] : b[r][j-1];
            float y0 = b[r][j];
            float yp = (j==7) ? rtb[r] : b[r][j+1];
            s2 += w2[r*3+0]*ym + w2[r*3+1]*y0 + w2[r*3+2]*yp;
        }
        float ge = 0.5f*s1*(1.f + erff(s1*0.70710678118654752f));
        o[j] = ge*s2;
    }
    st_bf8(g + (size_t)ch*NPIX + row*HW + col, o);
}

// ---------------- fo 1x1 conv (127 -> 48) + residual, 2px/thread ----------------
__global__ __launch_bounds__(256) void k_fo(const bf16* __restrict__ g,
                                            const float* __restrict__ W,
                                            const float* __restrict__ first,
                                            float* __restrict__ out)
{
    __shared__ float ws[48*128];
    for (int i = threadIdx.x; i < 48*128; i += 256) {
        int oc = i >> 7, ic = i & 127;
        ws[i] = (ic < 127) ? W[oc*127+ic] : 0.f;
    }
    __syncthreads();
    int p = (blockIdx.x*256 + threadIdx.x)*2;
    float acc0[48], acc1[48];
#pragma unroll
    for (int i = 0; i < 48; i++) { acc0[i] = 0.f; acc1[i] = 0.f; }
    for (int cb = 0; cb < 8; cb++) {
        float g0[16], g1[16];
#pragma unroll
        for (int j = 0; j < 16; j++) {
            int ic = cb*16 + j;
            if (ic < 127) {
                unsigned int word = *(const unsigned int*)&g[(size_t)ic*NPIX + p];
                fu c0, c1; c0.u = word << 16; c1.u = word & 0xffff0000u;
                g0[j] = c0.f; g1[j] = c1.f;
            } else { g0[j] = 0.f; g1[j] = 0.f; }
        }
        for (int oc = 0; oc < 48; oc++) {
            const float4* wr = (const float4*)&ws[oc*128 + cb*16];
            float a0 = acc0[oc], a1 = acc1[oc];
#pragma unroll
            for (int j = 0; j < 4; j++) {
                float4 w4 = wr[j];
                a0 += w4.x*g0[4*j] + w4.y*g0[4*j+1] + w4.z*g0[4*j+2] + w4.w*g0[4*j+3];
                a1 += w4.x*g1[4*j] + w4.y*g1[4*j+1] + w4.z*g1[4*j+2] + w4.w*g1[4*j+3];
            }
            acc0[oc] = a0; acc1[oc] = a1;
        }
    }
    for (int oc = 0; oc < 48; oc++) {
        float2 f = *(const float2*)&first[(size_t)oc*NPIX + p];
        f.x += acc0[oc]; f.y += acc1[oc];
        *(float2*)&out[(size_t)oc*NPIX + p] = f;
    }
}

extern "C" void kernel_launch(void* const* d_in, const int* in_sizes, int n_in,
                              void* d_out, int out_size, void* d_ws, size_t ws_size,
                              hipStream_t stream)
{
    const float* x     = (const float*)d_in[0];
    const float* pe_w  = (const float*)d_in[1];
    const float* n1w   = (const float*)d_in[2];
    const float* n1b   = (const float*)d_in[3];
    const float* temp  = (const float*)d_in[4];
    const float* qkvw  = (const float*)d_in[5];
    const float* qkvdw = (const float*)d_in[6];
    const float* pow_  = (const float*)d_in[7];
    const float* n2w   = (const float*)d_in[8];
    const float* n2b   = (const float*)d_in[9];
    const float* piw   = (const float*)d_in[10];
    const float* ffndw = (const float*)d_in[11];
    const float* fow   = (const float*)d_in[12];
    float* out = (float*)d_out;

    float* P  = (float*)d_ws;
    bf16*  A  = (bf16*)(P + (size_t)48*NPIX);
    bf16*  Bq = A + (size_t)144*NPIX;
    bf16*  H1 = A;
    bf16*  G  = A + (size_t)254*NPIX;          // ends at A + 381 planes
    bf16*  WQ = A + (size_t)381*NPIX;          // 144*64 bf16 (18 KB) in the hole before SM
    bf16*  WP = WQ + 144*64;                   // 256*64 bf16 (32 KB)
    float* SM = (float*)(A + (size_t)384*NPIX);
    float* sumsq = SM;
    float* S  = SM + 96;
    float* M  = SM + 96 + 2304;

    dim3 blk(256);
    int nb2 = NPIX/512;   // 2px/thread kernels
    int nb1 = NPIX/256;   // 1px/thread (MFMA ln_mm)
    int nr  = HW/4;       // wave-per-row kernels: 4 rows/block

    // one-time weight prep (same work every call — graph-safe)
    k_wprep<<<dim3(36), blk, 0, stream>>>(qkvw, WQ, 144, 144);
    k_wprep<<<dim3(64), blk, 0, stream>>>(piw, WP, 254, 256);

    for (int b = 0; b < 2; b++) {
        const float* xb   = x   + (size_t)b*3*NPIX;
        float*       outb = out + (size_t)b*48*NPIX;

        k_pe<<<dim3(nr), blk, 0, stream>>>(xb, pe_w, P);
        k_ln_mm_mfma<144,144,3><<<dim3(nb1), blk, 0, stream>>>(P, n1w, n1b, (const s16x8*)WQ, A);
        k_dw<<<dim3(nr, 144), blk, 0, stream>>>(A, qkvdw, Bq);
        k_zero<<<dim3(10), blk, 0, stream>>>(SM, 96 + 2304);
        k_sumsq<<<dim3(16, 96), blk, 0, stream>>>(Bq, sumsq);
        k_qkt<<<dim3(NPIX/QKT_PIX), blk, 0, stream>>>(Bq, Bq + (size_t)48*NPIX, S);
        k_attn_final<<<dim3(1), blk, 0, stream>>>(S, sumsq, pow_, temp, M);
        k_attnv<<<dim3(nb2), blk, 0, stream>>>(Bq + (size_t)96*NPIX, M, P);
        k_ln_mm_mfma<256,254,4><<<dim3(nb1), blk, 0, stream>>>(P, n2w, n2b, (const s16x8*)WP, H1);
        k_dw_glu<<<dim3(nr, 127), blk, 0, stream>>>(H1, ffndw, G);
        k_fo<<<dim3(nb2), blk, 0, stream>>>(G, fow, P, outb);
    }
}

// Round 6
// 1053.874 us; speedup vs baseline: 2.0353x; 1.1164x over previous
//
#include <hip/hip_runtime.h>
#include <hip/hip_bf16.h>
#include <math.h>

#define HW 512
#define NPIX (HW*HW)

typedef __hip_bfloat16 bf16;
typedef __attribute__((ext_vector_type(8))) unsigned short u16x8;
typedef __attribute__((ext_vector_type(8))) short s16x8;
typedef __attribute__((ext_vector_type(4))) float f32x4;

__device__ __forceinline__ float b2f(bf16 v) { return __bfloat162float(v); }
__device__ __forceinline__ bf16 f2b(float v) { return __float2bfloat16(v); }

union fu { float f; unsigned int u; };
union bu { bf16 b; unsigned short u; };

__device__ __forceinline__ void ld_bf8(const bf16* p, float* f) {
    u16x8 u = *(const u16x8*)p;
#pragma unroll
    for (int j = 0; j < 8; j++) { fu c; c.u = ((unsigned int)u[j]) << 16; f[j] = c.f; }
}

__device__ __forceinline__ void st_bf8(bf16* p, const float* f) {
    u16x8 u;
#pragma unroll
    for (int j = 0; j < 8; j++) { bu c; c.b = f2b(f[j]); u[j] = c.u; }
    *(u16x8*)p = u;
}

// ---------------- zero small accumulator region ----------------
__global__ __launch_bounds__(256) void k_zero(float* __restrict__ p, int n)
{
    int i = blockIdx.x*256 + threadIdx.x;
    if (i < n) p[i] = 0.f;
}

// ---------------- weight prep: fp32 [oc_real][kreal] -> bf16 [oc_pad][kpad] ----------------
__global__ __launch_bounds__(256) void k_wprep(const float* __restrict__ W,
                                               bf16* __restrict__ wpad,
                                               int kreal, int kpad, int oc_real, int oc_pad)
{
    int idx = blockIdx.x*256 + threadIdx.x;
    if (idx >= oc_pad*kpad) return;
    int oc = idx / kpad, k = idx - oc*kpad;
    float v = (oc < oc_real && k < kreal) ? W[oc*kreal + k] : 0.f;
    wpad[idx] = f2b(v);
}

// ---------------- patch embed: 3x3 conv, 3 -> 48 (wave-per-row, 8px/lane), bf16 out ----------------
__global__ __launch_bounds__(256) void k_pe(const float* __restrict__ x,
                                            const float* __restrict__ w,
                                            bf16* __restrict__ out)
{
    __shared__ float ws[48*27];
    for (int i = threadIdx.x; i < 48*27; i += 256) ws[i] = w[i];
    __syncthreads();
    int lane = threadIdx.x & 63, wv = threadIdx.x >> 6;
    int row = blockIdx.x*4 + wv;
    int col = lane*8;
    float a[3][3][8];
    float lf[3][3], rt[3][3];
#pragma unroll
    for (int c = 0; c < 3; c++)
#pragma unroll
        for (int r = 0; r < 3; r++) {
            int rr = row + r - 1;
            if (rr >= 0 && rr < HW) {
                const float* p = x + (size_t)c*NPIX + rr*HW + col;
                float4 u0 = *(const float4*)p, u1 = *(const float4*)(p+4);
                a[c][r][0]=u0.x; a[c][r][1]=u0.y; a[c][r][2]=u0.z; a[c][r][3]=u0.w;
                a[c][r][4]=u1.x; a[c][r][5]=u1.y; a[c][r][6]=u1.z; a[c][r][7]=u1.w;
            } else {
#pragma unroll
                for (int j = 0; j < 8; j++) a[c][r][j] = 0.f;
            }
            float l = __shfl_up(a[c][r][7], 1);  lf[c][r] = (lane==0)  ? 0.f : l;
            float rv= __shfl_down(a[c][r][0],1); rt[c][r] = (lane==63) ? 0.f : rv;
        }
    for (int oc = 0; oc < 48; oc++) {
        float acc[8];
#pragma unroll
        for (int j = 0; j < 8; j++) acc[j] = 0.f;
#pragma unroll
        for (int c = 0; c < 3; c++)
#pragma unroll
            for (int r = 0; r < 3; r++) {
                float w0 = ws[oc*27 + c*9 + r*3 + 0];
                float w1 = ws[oc*27 + c*9 + r*3 + 1];
                float w2 = ws[oc*27 + c*9 + r*3 + 2];
#pragma unroll
                for (int j = 0; j < 8; j++) {
                    float xm = (j==0) ? lf[c][r] : a[c][r][j-1];
                    float x0 = a[c][r][j];
                    float xp = (j==7) ? rt[c][r] : a[c][r][j+1];
                    acc[j] += w0*xm + w1*x0 + w2*xp;
                }
            }
        st_bf8(out + (size_t)oc*NPIX + row*HW + col, acc);
    }
}

// ---------------- fused channel-LayerNorm + 1x1 conv via MFMA (48 -> OC), bf16 in/out ----------------
template<int OC_PAD, int OC_REAL, int MT_PER_WAVE>
__global__ __launch_bounds__(256) void k_ln_mm_mfma(const bf16* __restrict__ in,
                                                    const float* __restrict__ lnw,
                                                    const float* __restrict__ lnb,
                                                    const s16x8* __restrict__ wpad,  // [OC_PAD][8 blocks]
                                                    bf16* __restrict__ out)
{
    constexpr int NMT = OC_PAD/16;
    __shared__ s16x8 y_lds[256*8];
    __shared__ float lw[48], lb[48];
    int t = threadIdx.x;
    if (t < 48) { lw[t] = lnw[t]; lb[t] = lnb[t]; }
    int base = blockIdx.x*256;
    int px = base + t;
    float y[48];
    float mu = 0.f;
#pragma unroll
    for (int i = 0; i < 48; i++) { y[i] = b2f(in[(size_t)i*NPIX + px]); mu += y[i]; }
    mu *= (1.f/48.f);
    float var = 0.f;
#pragma unroll
    for (int i = 0; i < 48; i++) { float d = y[i]-mu; var += d*d; }
    float s = rsqrtf(var*(1.f/48.f) + 1e-5f);
    __syncthreads();   // lw/lb visible
#pragma unroll
    for (int i = 0; i < 48; i++) y[i] = (y[i]-mu)*s*lw[i] + lb[i];
#pragma unroll
    for (int kb = 0; kb < 8; kb++) {
        union { s16x8 v; unsigned short us[8]; } pk;
#pragma unroll
        for (int j = 0; j < 8; j++) {
            int c = kb*8 + j;
            bu b; b.b = f2b(c < 48 ? y[c] : 0.f);
            pk.us[j] = (c < 48) ? b.u : (unsigned short)0;
        }
        y_lds[t*8 + (kb ^ (t & 7))] = pk.v;
    }
    __syncthreads();

    int lane = t & 63, wv = t >> 6;
    int q = lane >> 4, n = lane & 15;
    s16x8 a[MT_PER_WAVE][2];
#pragma unroll
    for (int mi = 0; mi < MT_PER_WAVE; mi++) {
        int mt = wv + 4*mi;
        if (mt < NMT) {
            int oc = mt*16 + n;
            a[mi][0] = wpad[oc*8 + q];
            a[mi][1] = wpad[oc*8 + 4 + q];
        }
    }
#pragma unroll 1
    for (int nt = 0; nt < 16; nt++) {
        int npx = nt*16 + n;
        s16x8 b0 = y_lds[npx*8 + (q ^ (npx & 7))];
        s16x8 b1 = y_lds[npx*8 + ((4 + q) ^ (npx & 7))];
        size_t pxg = base + npx;
#pragma unroll
        for (int mi = 0; mi < MT_PER_WAVE; mi++) {
            int mt = wv + 4*mi;
            if (mt >= NMT) continue;
            f32x4 acc = {0.f, 0.f, 0.f, 0.f};
            acc = __builtin_amdgcn_mfma_f32_16x16x32_bf16(a[mi][0], b0, acc, 0, 0, 0);
            acc = __builtin_amdgcn_mfma_f32_16x16x32_bf16(a[mi][1], b1, acc, 0, 0, 0);
            int ocb = mt*16 + q*4;
#pragma unroll
            for (int r = 0; r < 4; r++) {
                int oc = ocb + r;
                if (OC_REAL == OC_PAD || oc < OC_REAL)
                    out[(size_t)oc*NPIX + pxg] = f2b(acc[r]);
            }
        }
    }
}

// ---------------- depthwise 3x3 (bf16 -> bf16), wave-per-row 8px/lane ----------------
__global__ __launch_bounds__(256) void k_dw(const bf16* __restrict__ in,
                                            const float* __restrict__ w,
                                            bf16* __restrict__ out)
{
    int ch = blockIdx.y;
    int lane = threadIdx.x & 63, wv = threadIdx.x >> 6;
    int row = blockIdx.x*4 + wv;
    int col = lane*8;
    const bf16* ip = in + (size_t)ch*NPIX;
    float wk[9];
#pragma unroll
    for (int i = 0; i < 9; i++) wk[i] = w[ch*9+i];
    float a[3][8];
    float lf[3], rt[3];
#pragma unroll
    for (int r = 0; r < 3; r++) {
        int rr = row + r - 1;
        if (rr >= 0 && rr < HW) ld_bf8(ip + rr*HW + col, a[r]);
        else { for (int j = 0; j < 8; j++) a[r][j] = 0.f; }
        float l = __shfl_up(a[r][7], 1);  lf[r] = (lane==0)  ? 0.f : l;
        float rv= __shfl_down(a[r][0],1); rt[r] = (lane==63) ? 0.f : rv;
    }
    float o[8];
#pragma unroll
    for (int j = 0; j < 8; j++) {
        float s = 0.f;
#pragma unroll
        for (int r = 0; r < 3; r++) {
            float xm = (j==0) ? lf[r] : a[r][j-1];
            float x0 = a[r][j];
            float xp = (j==7) ? rt[r] : a[r][j+1];
            s += wk[r*3+0]*xm + wk[r*3+1]*x0 + wk[r*3+2]*xp;
        }
        o[j] = s;
    }
    st_bf8(out + (size_t)ch*NPIX + row*HW + col, o);
}

// ---------------- S = Q K^T (48x48) + per-channel sumsq of q,k, fused ----------------
#define QKT_PIX 2048
__global__ __launch_bounds__(256) void k_qkt(const bf16* __restrict__ q,
                                             const bf16* __restrict__ k,
                                             float* __restrict__ S,
                                             float* __restrict__ sumsq)
{
    __shared__ float qs[48][65];
    __shared__ float ks[48][65];
    int t = threadIdx.x;
    int tx = t & 15, ty = t >> 4;
    int lane = t & 63, wv = t >> 6;
    float acc[3][3];
#pragma unroll
    for (int i = 0; i < 3; i++)
#pragma unroll
        for (int j = 0; j < 3; j++) acc[i][j] = 0.f;
    float sq[12], sk[12];
#pragma unroll
    for (int i = 0; i < 12; i++) { sq[i] = 0.f; sk[i] = 0.f; }

    int base0 = blockIdx.x * QKT_PIX;
    for (int base = base0; base < base0 + QKT_PIX; base += 64) {
#pragma unroll
        for (int it = 0; it < 12; it++) {
            int c  = wv + (it << 2);
            qs[c][lane] = b2f(q[(size_t)c*NPIX + base + lane]);
            ks[c][lane] = b2f(k[(size_t)c*NPIX + base + lane]);
        }
        __syncthreads();
        // sumsq accumulation: wave wv owns channels wv+4i
#pragma unroll
        for (int i = 0; i < 12; i++) {
            int c = wv + 4*i;
            float qv = qs[c][lane]; sq[i] += qv*qv;
            float kv = ks[c][lane]; sk[i] += kv*kv;
        }
#pragma unroll 4
        for (int pp = 0; pp < 64; pp++) {
            float qv[3], kv[3];
#pragma unroll
            for (int i = 0; i < 3; i++) { qv[i] = qs[ty+16*i][pp]; kv[i] = ks[tx+16*i][pp]; }
#pragma unroll
            for (int i = 0; i < 3; i++)
#pragma unroll
                for (int j = 0; j < 3; j++) acc[i][j] += qv[i]*kv[j];
        }
        __syncthreads();
    }
#pragma unroll
    for (int i = 0; i < 3; i++)
#pragma unroll
        for (int j = 0; j < 3; j++)
            atomicAdd(&S[(ty+16*i)*48 + (tx+16*j)], acc[i][j]);
#pragma unroll
    for (int i = 0; i < 12; i++) {
        float a = sq[i], b = sk[i];
#pragma unroll
        for (int off = 32; off; off >>= 1) { a += __shfl_down(a, off); b += __shfl_down(b, off); }
        if (lane == 0) {
            atomicAdd(&sumsq[wv + 4*i], a);
            atomicAdd(&sumsq[48 + wv + 4*i], b);
        }
    }
}

// ---------------- finalize: normalize, softmax, M = po_w @ attn ----------------
__global__ __launch_bounds__(256) void k_attn_final(const float* __restrict__ S,
                                                    const float* __restrict__ sumsq,
                                                    const float* __restrict__ po_w,
                                                    const float* __restrict__ temp,
                                                    float* __restrict__ M)
{
    __shared__ float attn[48][48];
    __shared__ float nrm[96];
    int t = threadIdx.x;
    if (t < 96) nrm[t] = fmaxf(sqrtf(sumsq[t]), 1e-12f);
    __syncthreads();
    float tmp = temp[0];
    if (t < 48) {
        float row[48];
        float mx = -1e30f;
#pragma unroll
        for (int d = 0; d < 48; d++) {
            float l = S[t*48+d] / (nrm[t]*nrm[48+d]) * tmp;
            row[d] = l; mx = fmaxf(mx, l);
        }
        float sum = 0.f;
#pragma unroll
        for (int d = 0; d < 48; d++) { float e = expf(row[d]-mx); sum += e; row[d] = e; }
        float inv = 1.f/sum;
#pragma unroll
        for (int d = 0; d < 48; d++) attn[t][d] = row[d]*inv;
    }
    __syncthreads();
    for (int idx = t; idx < 2304; idx += 256) {
        int cp = idx/48, d = idx%48;
        float acc = 0.f;
#pragma unroll
        for (int c = 0; c < 48; c++) acc += po_w[cp*48+c] * attn[c][d];
        M[idx] = acc;
    }
}

// ---------------- first = patch + M @ v (in place over bf16 patch, 2px/thread) ----------------
__global__ __launch_bounds__(256) void k_attnv(const bf16* __restrict__ v,
                                               const float* __restrict__ M,
                                               bf16* __restrict__ patch)
{
    __shared__ float Ms[48*48];
    for (int i = threadIdx.x; i < 2304; i += 256) Ms[i] = M[i];
    __syncthreads();
    int p = (blockIdx.x*256 + threadIdx.x)*2;
    float v0[48], v1[48];
#pragma unroll
    for (int i = 0; i < 48; i++) {
        unsigned int word = *(const unsigned int*)&v[(size_t)i*NPIX + p];
        fu c0, c1; c0.u = word << 16; c1.u = word & 0xffff0000u;
        v0[i] = c0.f; v1[i] = c1.f;
    }
    for (int oc = 0; oc < 48; oc++) {
        const float4* wr = (const float4*)&Ms[oc*48];
        float a0 = 0.f, a1 = 0.f;
#pragma unroll
        for (int i = 0; i < 12; i++) {
            float4 w4 = wr[i];
            a0 += w4.x*v0[4*i] + w4.y*v0[4*i+1] + w4.z*v0[4*i+2] + w4.w*v0[4*i+3];
            a1 += w4.x*v1[4*i] + w4.y*v1[4*i+1] + w4.z*v1[4*i+2] + w4.w*v1[4*i+3];
        }
        unsigned int* pp = (unsigned int*)&patch[(size_t)oc*NPIX + p];
        unsigned int old = *pp;
        fu f0, f1; f0.u = old << 16; f1.u = old & 0xffff0000u;
        bu b0, b1; b0.b = f2b(f0.f + a0); b1.b = f2b(f1.f + a1);
        *pp = (unsigned int)b0.u | ((unsigned int)b1.u << 16);
    }
}

// ---------------- depthwise 3x3 both halves + gelu(x1)*x2, wave-per-row ----------------
__global__ __launch_bounds__(256) void k_dw_glu(const bf16* __restrict__ h1,
                                                const float* __restrict__ w,
                                                bf16* __restrict__ g)
{
    int ch = blockIdx.y;   // 0..126
    int lane = threadIdx.x & 63, wv = threadIdx.x >> 6;
    int row = blockIdx.x*4 + wv;
    int col = lane*8;
    float w1[9], w2[9];
#pragma unroll
    for (int i = 0; i < 9; i++) { w1[i] = w[ch*9+i]; w2[i] = w[(ch+127)*9+i]; }
    const bf16* i1 = h1 + (size_t)ch*NPIX;
    const bf16* i2 = h1 + (size_t)(ch+127)*NPIX;
    float a[3][8], b[3][8];
    float lfa[3], rta[3], lfb[3], rtb[3];
#pragma unroll
    for (int r = 0; r < 3; r++) {
        int rr = row + r - 1;
        if (rr >= 0 && rr < HW) {
            ld_bf8(i1 + rr*HW + col, a[r]);
            ld_bf8(i2 + rr*HW + col, b[r]);
        } else {
#pragma unroll
            for (int j = 0; j < 8; j++) { a[r][j] = 0.f; b[r][j] = 0.f; }
        }
        float l1 = __shfl_up(a[r][7],1);   lfa[r] = (lane==0)  ? 0.f : l1;
        float r1 = __shfl_down(a[r][0],1); rta[r] = (lane==63) ? 0.f : r1;
        float l2 = __shfl_up(b[r][7],1);   lfb[r] = (lane==0)  ? 0.f : l2;
        float r2 = __shfl_down(b[r][0],1); rtb[r] = (lane==63) ? 0.f : r2;
    }
    float o[8];
#pragma unroll
    for (int j = 0; j < 8; j++) {
        float s1 = 0.f, s2 = 0.f;
#pragma unroll
        for (int r = 0; r < 3; r++) {
            float xm = (j==0) ? lfa[r] : a[r][j-1];
            float x0 = a[r][j];
            float xp = (j==7) ? rta[r] : a[r][j+1];
            s1 += w1[r*3+0]*xm + w1[r*3+1]*x0 + w1[r*3+2]*xp;
            float ym = (j==0) ? lfb[r] : b[r][j-1];
            float y0 = b[r][j];
            float yp = (j==7) ? rtb[r] : b[r][j+1];
            s2 += w2[r*3+0]*ym + w2[r*3+1]*y0 + w2[r*3+2]*yp;
        }
        float ge = 0.5f*s1*(1.f + erff(s1*0.70710678118654752f));
        o[j] = ge*s2;
    }
    st_bf8(g + (size_t)ch*NPIX + row*HW + col, o);
}

// ---------------- fo 1x1 conv (127 -> 48) via MFMA + residual, fp32 out ----------------
__global__ __launch_bounds__(256) void k_fo_mfma(const bf16* __restrict__ g,
                                                 const s16x8* __restrict__ wfo,   // [48][16 blocks]
                                                 const bf16* __restrict__ first,
                                                 float* __restrict__ out)
{
    __shared__ s16x8 glds[256*16];   // 64 KB, swizzled
    int t = threadIdx.x;
    int base = blockIdx.x*256;
    int px = base + t;
#pragma unroll
    for (int kb = 0; kb < 16; kb++) {
        union { s16x8 v; unsigned short us[8]; } pk;
#pragma unroll
        for (int j = 0; j < 8; j++) {
            int c = kb*8 + j;
            if (c < 127) { bu b; b.b = g[(size_t)c*NPIX + px]; pk.us[j] = b.u; }
            else pk.us[j] = 0;
        }
        glds[t*16 + (kb ^ (t & 15))] = pk.v;
    }
    __syncthreads();
    int lane = t & 63, wv = t >> 6;
    int q = lane >> 4, n = lane & 15;
    s16x8 a[3][4];
#pragma unroll
    for (int mt = 0; mt < 3; mt++) {
        int oc = mt*16 + n;
#pragma unroll
        for (int kc = 0; kc < 4; kc++)
            a[mt][kc] = wfo[oc*16 + kc*4 + q];
    }
#pragma unroll 1
    for (int ni = 0; ni < 4; ni++) {
        int nt = wv*4 + ni;
        int npx = nt*16 + n;
        s16x8 b[4];
#pragma unroll
        for (int kc = 0; kc < 4; kc++)
            b[kc] = glds[npx*16 + ((kc*4 + q) ^ (npx & 15))];
        size_t pxg = base + npx;
#pragma unroll
        for (int mt = 0; mt < 3; mt++) {
            f32x4 acc = {0.f, 0.f, 0.f, 0.f};
#pragma unroll
            for (int kc = 0; kc < 4; kc++)
                acc = __builtin_amdgcn_mfma_f32_16x16x32_bf16(a[mt][kc], b[kc], acc, 0, 0, 0);
            int ocb = mt*16 + q*4;
#pragma unroll
            for (int r = 0; r < 4; r++) {
                int oc = ocb + r;
                out[(size_t)oc*NPIX + pxg] = b2f(first[(size_t)oc*NPIX + pxg]) + acc[r];
            }
        }
    }
}

extern "C" void kernel_launch(void* const* d_in, const int* in_sizes, int n_in,
                              void* d_out, int out_size, void* d_ws, size_t ws_size,
                              hipStream_t stream)
{
    const float* x     = (const float*)d_in[0];
    const float* pe_w  = (const float*)d_in[1];
    const float* n1w   = (const float*)d_in[2];
    const float* n1b   = (const float*)d_in[3];
    const float* temp  = (const float*)d_in[4];
    const float* qkvw  = (const float*)d_in[5];
    const float* qkvdw = (const float*)d_in[6];
    const float* pow_  = (const float*)d_in[7];
    const float* n2w   = (const float*)d_in[8];
    const float* n2b   = (const float*)d_in[9];
    const float* piw   = (const float*)d_in[10];
    const float* ffndw = (const float*)d_in[11];
    const float* fow   = (const float*)d_in[12];
    float* out = (float*)d_out;

    // ws layout in bf16 planes (0.5 MiB each), per-batch reuse (~217 MiB):
    //   Pb : planes   0..47    patch -> first (bf16)
    //   A  : planes  48..191   qkv pre-dw
    //   Bq : planes 192..335   qkv post-dw (q,k,v; v = 288..335)
    //   H1 : planes  48..301   GDFN pre-dw (after attnv retires q,k,v region use)
    //   G  : planes 302..428   gelu(x1)*x2
    //   WQ/WP/WF : packed weights after G;  SM : fp32 scalars at plane 432
    bf16*  Pb = (bf16*)d_ws;
    bf16*  A  = Pb + (size_t)48*NPIX;
    bf16*  Bq = A + (size_t)144*NPIX;
    bf16*  H1 = A;
    bf16*  G  = A + (size_t)254*NPIX;
    bf16*  WQ = A + (size_t)381*NPIX;          // 144*64
    bf16*  WP = WQ + 144*64;                   // 256*64
    bf16*  WF = WP + 256*64;                   // 48*128
    float* SM = (float*)(A + (size_t)384*NPIX);
    float* sumsq = SM;
    float* S  = SM + 96;
    float* M  = SM + 96 + 2304;

    dim3 blk(256);
    int nb2 = NPIX/512;   // 2px/thread kernels
    int nb1 = NPIX/256;   // 1px/thread (MFMA kernels)
    int nr  = HW/4;       // wave-per-row kernels: 4 rows/block

    // weight prep (same work every call — graph-safe)
    k_wprep<<<dim3(36), blk, 0, stream>>>(qkvw, WQ, 48, 64, 144, 144);
    k_wprep<<<dim3(64), blk, 0, stream>>>(piw,  WP, 48, 64, 254, 256);
    k_wprep<<<dim3(24), blk, 0, stream>>>(fow,  WF, 127, 128, 48, 48);

    for (int b = 0; b < 2; b++) {
        const float* xb   = x   + (size_t)b*3*NPIX;
        float*       outb = out + (size_t)b*48*NPIX;

        k_pe<<<dim3(nr), blk, 0, stream>>>(xb, pe_w, Pb);
        k_ln_mm_mfma<144,144,3><<<dim3(nb1), blk, 0, stream>>>(Pb, n1w, n1b, (const s16x8*)WQ, A);
        k_dw<<<dim3(nr, 144), blk, 0, stream>>>(A, qkvdw, Bq);
        k_zero<<<dim3(10), blk, 0, stream>>>(SM, 96 + 2304);
        k_qkt<<<dim3(NPIX/QKT_PIX), blk, 0, stream>>>(Bq, Bq + (size_t)48*NPIX, S, sumsq);
        k_attn_final<<<dim3(1), blk, 0, stream>>>(S, sumsq, pow_, temp, M);
        k_attnv<<<dim3(nb2), blk, 0, stream>>>(Bq + (size_t)96*NPIX, M, Pb);
        k_ln_mm_mfma<256,254,4><<<dim3(nb1), blk, 0, stream>>>(Pb, n2w, n2b, (const s16x8*)WP, H1);
        k_dw_glu<<<dim3(nr, 127), blk, 0, stream>>>(H1, ffndw, G);
        k_fo_mfma<<<dim3(nb1), blk, 0, stream>>>(G, (const s16x8*)WF, Pb, outb);
    }
}